// Round 14
// baseline (145.680 us; speedup 1.0000x reference)
//
#include <hip/hip_runtime.h>
#include <hip/hip_bf16.h>

typedef unsigned short u16;
typedef unsigned int u32;
typedef __attribute__((ext_vector_type(8))) short bf16x8;
typedef __attribute__((ext_vector_type(4))) float f32x4;

#define HD 64
#define NH 16
#define TT 2048
#define BB 2
#define CA 1280

__device__ __forceinline__ u16 bfu(float f) {
    u32 u = __builtin_bit_cast(u32, f);
    u32 r = u + 0x7fffu + ((u >> 16) & 1u);
    return (u16)(r >> 16);
}

__device__ __forceinline__ float ex2(float x) {
#if __has_builtin(__builtin_amdgcn_exp2f)
    return __builtin_amdgcn_exp2f(x);
#else
    return exp2f(x);
#endif
}

__device__ __forceinline__ void gload16(const void* g, void* l) {
    __builtin_amdgcn_global_load_lds(
        (const __attribute__((address_space(1))) unsigned int*)g,
        (__attribute__((address_space(3))) unsigned int*)l,
        16, 0, 0);
}

// ------------- fused prep: [0,5120) build_xaug | [5120,10240) wtrans x4 | [10240,11264) pack_mask
__global__ void prep(const float* __restrict__ x, const float* __restrict__ aux,
                     u16* __restrict__ xa,
                     const float* __restrict__ Wq, const float* __restrict__ Wk,
                     const float* __restrict__ Wv, const float* __restrict__ Wo,
                     u16* __restrict__ WTall, u16* __restrict__ WTo,
                     const unsigned char* __restrict__ m, u32* __restrict__ bits) {
    int bid = blockIdx.x;
    if (bid < 5120) {
        // ---- build x_aug (bf16 [4096][1280]) ----
        int i = bid * 256 + threadIdx.x;          // over 4096*320 float4 slots
        int row = i / 320;
        int c4 = i - row * 320;
        float4 v;
        if (c4 < 256) v = ((const float4*)x)[row * 256 + c4];
        else          v = ((const float4*)aux)[row * 64 + (c4 - 256)];
        ushort4 pk; pk.x = bfu(v.x); pk.y = bfu(v.y); pk.z = bfu(v.z); pk.w = bfu(v.w);
        ((ushort4*)xa)[i] = pk;
    } else if (bid < 10240) {
        // ---- weight transpose fp32 [Ksrc][1024] -> bf16 [1024][Kpad] ----
        int t = bid - 5120;
        int z = t / 1280;
        int inner = t - z * 1280;
        int kt = (inner % 40) * 32;
        int nt = (inner / 40) * 32;
        const float* src = (z == 0) ? Wq : (z == 1) ? Wk : (z == 2) ? Wv : Wo;
        u16* dst = (z == 3) ? WTo : WTall + (size_t)z * 1024 * 1280;
        int Ksrc = (z == 0 || z == 3) ? 1024 : 1280;
        int Kpad = (z == 3) ? 1024 : 1280;
        if (kt >= Kpad) return;
        __shared__ float tile[32][33];
        int r = threadIdx.x >> 5, c = threadIdx.x & 31;
        #pragma unroll
        for (int i = 0; i < 4; i++) {
            int k = kt + r + i * 8;
            tile[r + i * 8][c] = (k < Ksrc) ? src[(size_t)k * 1024 + nt + c] : 0.f;
        }
        __syncthreads();
        #pragma unroll
        for (int i = 0; i < 4; i++) {
            int n = nt + r + i * 8;
            dst[(size_t)n * Kpad + kt + c] = bfu(tile[c][r + i * 8]);
        }
    } else {
        // ---- pack mask -> bitmask [B][T][64 u32], runtime dtype detect ----
        __shared__ u32 modeSh;
        if (threadIdx.x == 0) modeSh = 0;
        __syncthreads();
        const u32* wp = (const u32*)m;
        u32 local = 0;
        for (int j = threadIdx.x; j < 2048; j += 256) {
            u32 v = wp[j];
            if (v == 0x3f800000u) local |= 2u;        // float32 1.0 word
            else if (v > 1u) local |= 1u;             // byte-packed bools
            if ((j & 1) && v != 0u) local |= 4u;      // odd word nonzero -> not int64
        }
        if (local) atomicOr(&modeSh, local);
        __syncthreads();
        u32 mode = modeSh;
        bool words32 = (mode & 2u) || (mode == 4u);   // float32 or int32
        bool bytes8 = !words32 && (mode & 1u);        // uint8 bools

        int i = (bid - 10240) * 256 + threadIdx.x;    // over B*T*64 = 262144
        size_t e0 = (size_t)i * 32;
        u32 r = 0;
        if (words32) {
            const uint4* q = (const uint4*)(wp + e0);
            #pragma unroll
            for (int j4 = 0; j4 < 8; j4++) {
                uint4 v = q[j4];
                if (v.x) r |= 1u << (j4 * 4 + 0);
                if (v.y) r |= 1u << (j4 * 4 + 1);
                if (v.z) r |= 1u << (j4 * 4 + 2);
                if (v.w) r |= 1u << (j4 * 4 + 3);
            }
        } else if (bytes8) {
            const unsigned char* p = m + e0;
            uint4 a = *(const uint4*)p;
            uint4 b = *(const uint4*)(p + 16);
            u32 words[8] = {a.x, a.y, a.z, a.w, b.x, b.y, b.z, b.w};
            #pragma unroll
            for (int jw = 0; jw < 8; jw++) {
                u32 xw = words[jw];
                r |= ((xw >> 0) & 1u) << (jw * 4 + 0);
                r |= ((xw >> 8) & 1u) << (jw * 4 + 1);
                r |= ((xw >> 16) & 1u) << (jw * 4 + 2);
                r |= ((xw >> 24) & 1u) << (jw * 4 + 3);
            }
        } else {
            #pragma unroll 4
            for (int j = 0; j < 32; j++)
                if (wp[(e0 + j) * 2]) r |= 1u << j;
        }
        bits[i] = r;
    }
}

// ---------------- GEMM: A[M][ld] bf16 row-major, Bt[N][ld] bf16 row-major ----------------
// MODE 0: flat grid 768 with XCD bm-strip swizzle. sec = bn>>3 uniform per block:
//   sec 0: q = (acc+bias+PE)*0.125*log2e -> [B,H,T,64]; Keff=1024 (Wq pad x aux = 0)
//   sec 1: k = acc+bias+PE               -> [B,H,T,64]
//   sec 2: v = acc+bias, written TRANSPOSED -> VT [B,H,64,T]
// MODE 1: dim3 grid, fp32 out + bias
template <int MODE>
__global__ __launch_bounds__(256, 3) void gemm_bt(
    const u16* __restrict__ A, const u16* __restrict__ Bt, int K,
    const float* __restrict__ biasq, const float* __restrict__ biask,
    const float* __restrict__ biasv, const float* __restrict__ PEq,
    const float* __restrict__ PEk, const int* __restrict__ fidx,
    u16* __restrict__ qo, u16* __restrict__ ko, u16* __restrict__ vto,
    float* __restrict__ fo, const float* __restrict__ bo) {
    __shared__ u16 As[128 * 64];
    __shared__ u16 Bs[128 * 64];
    const int tid = threadIdx.x, lane = tid & 63, w = tid >> 6;
    const int l15 = lane & 15, l4 = lane >> 4;
    const int wm = w >> 1, wn = w & 1;
    int bm, bn;
    if (MODE == 0) {
        int bid = blockIdx.x;                      // 768 flat
        bm = (bid & 7) * 4 + ((bid >> 3) & 3);     // XCD strip: 4 bm per XCD
        bn = bid >> 5;
    } else {
        bm = blockIdx.x; bn = blockIdx.y;
    }
    const int Keff = (MODE == 0 && (bn >> 3) == 0) ? 1024 : K;

    f32x4 acc[4][4] = {};

    const int srow = lane >> 3;
    const int schunk = (lane & 7) ^ srow;
    const u16* ag = A + (size_t)(bm * 128 + w * 32 + srow) * K + schunk * 8;
    const u16* bg = Bt + (size_t)(bn * 128 + w * 32 + srow) * K + schunk * 8;
    u16* asl = &As[(w * 32) * 64] + lane * 8;
    u16* bsl = &Bs[(w * 32) * 64] + lane * 8;

    for (int kt = 0; kt < Keff; kt += 64) {
        #pragma unroll
        for (int i = 0; i < 4; i++) {
            gload16(ag + (size_t)i * 8 * K + kt, asl + i * 8 * 64);
            gload16(bg + (size_t)i * 8 * K + kt, bsl + i * 8 * 64);
        }
        __syncthreads();
        #pragma unroll
        for (int ks = 0; ks < 2; ks++) {
            bf16x8 af[4], bfr[4];
            #pragma unroll
            for (int mi = 0; mi < 4; mi++) {
                int row = wm * 64 + mi * 16 + l15;
                af[mi] = *(const bf16x8*)&As[row * 64 + (((ks * 4 + l4) ^ (row & 7)) * 8)];
            }
            #pragma unroll
            for (int ni = 0; ni < 4; ni++) {
                int row = wn * 64 + ni * 16 + l15;
                bfr[ni] = *(const bf16x8*)&Bs[row * 64 + (((ks * 4 + l4) ^ (row & 7)) * 8)];
            }
            #pragma unroll
            for (int mi = 0; mi < 4; mi++)
                #pragma unroll
                for (int ni = 0; ni < 4; ni++)
                    acc[mi][ni] = __builtin_amdgcn_mfma_f32_16x16x32_bf16(
                        af[mi], bfr[ni], acc[mi][ni], 0, 0, 0);
        }
        __syncthreads();
    }

    if (MODE == 0) {
        int sec = bn >> 3;
        if (sec < 2) {
            const float* bias = sec ? biask : biasq;
            const float* PE   = sec ? PEk : PEq;
            u16* outp = sec ? ko : qo;
            float scl = sec ? 1.0f : 0.180336880111120419f;   // q: 0.125*log2(e)
            #pragma unroll
            for (int mi = 0; mi < 4; mi++) {
                #pragma unroll
                for (int r = 0; r < 4; r++) {
                    int m = bm * 128 + wm * 64 + mi * 16 + l4 * 4 + r;
                    int b = m >> 11, t = m & 2047;
                    int fi = fidx[m];
                    #pragma unroll
                    for (int ni = 0; ni < 4; ni++) {
                        int nn = (bn & 7) * 128 + wn * 64 + ni * 16 + l15;
                        float val = (acc[mi][ni][r] + bias[nn] + PE[(size_t)fi * 1024 + nn]) * scl;
                        outp[((size_t)(b * NH + (nn >> 6)) * TT + t) * HD + (nn & 63)] = bfu(val);
                    }
                }
            }
        } else {
            // V: bias + transposed write. t runs over r (consecutive) -> ushort4 store.
            int b = bm >> 4;
            int t0 = (bm & 15) * 128 + wm * 64;
            #pragma unroll
            for (int ni = 0; ni < 4; ni++) {
                int nn = (bn - 16) * 128 + wn * 64 + ni * 16 + l15;
                float bvv = biasv[nn];
                int h = nn >> 6, d = nn & 63;
                u16* dst = vto + ((size_t)((b * NH + h) * HD + d)) * TT + t0;
                #pragma unroll
                for (int mi = 0; mi < 4; mi++) {
                    ushort4 pk;
                    pk.x = bfu(acc[mi][ni][0] + bvv);
                    pk.y = bfu(acc[mi][ni][1] + bvv);
                    pk.z = bfu(acc[mi][ni][2] + bvv);
                    pk.w = bfu(acc[mi][ni][3] + bvv);
                    *(ushort4*)(dst + mi * 16 + l4 * 4) = pk;
                }
            }
        }
    } else {
        #pragma unroll
        for (int mi = 0; mi < 4; mi++) {
            #pragma unroll
            for (int r = 0; r < 4; r++) {
                int m = bm * 128 + wm * 64 + mi * 16 + l4 * 4 + r;
                #pragma unroll
                for (int ni = 0; ni < 4; ni++) {
                    int ng = bn * 128 + wn * 64 + ni * 16 + l15;
                    fo[(size_t)m * 1024 + ng] = acc[mi][ni][r] + bo[ng];
                }
            }
        }
    }
}

// ---------------- flash attention (KVBLK=64 double-buffered, 1 barrier/tile) ----------
// r13 was barrier-drain bound: each tile's first __syncthreads sits right after the
// global_load_lds batch, exposing full L2 latency (compiler emits vmcnt(0) before
// s_barrier). Fix: KVBLK=64 with double-buffered K,V tiles ([64][64] each, identical
// stage/read swizzle) — prefetch of tile kt+1 issues at the TOP of tile kt, so the
// drain lands after a whole tile of compute. P in its own slab (wave-private rows,
// in-wave lgkm ordering) removes the union mid-barrier: ONE barrier per tile (33 vs 48).
// LDS: Ks 2x8KB + Vs 2x8KB + Ps [128][72] 18KB = 51200B (same as r13, 2 blk/CU grid-bound).
// grid flat 512 XCD-pinned: bh = (s&7)*4 + (s>>7), qt = (s>>3)&15; 4 waves x 32 q-rows.
__global__ __launch_bounds__(256, 2) void attn_fwd(
    const u16* __restrict__ Q, const u16* __restrict__ Kg,
    const u16* __restrict__ VT, const u32* __restrict__ mbits,
    u16* __restrict__ Og) {
    __shared__ u16 Ks[2][64 * 64];
    __shared__ u16 Vs[2][64 * 64];
    __shared__ u16 Ps[128 * 72];
    const int tid = threadIdx.x, lane = tid & 63, w = tid >> 6;
    const int l15 = lane & 15, l4 = lane >> 4;
    const int s_ = blockIdx.x;
    const int qt = (s_ >> 3) & 15;
    const int bh = (s_ & 7) * 4 + (s_ >> 7);
    const int b = bh >> 4;
    const size_t hoff = (size_t)bh * (TT * HD);

    // wave w owns q-rows qt*128 + w*32 + [0,32): two 16-row blocks (mi)
    bf16x8 qf[2][2];
    #pragma unroll
    for (int mi = 0; mi < 2; mi++)
        #pragma unroll
        for (int ks = 0; ks < 2; ks++)
            qf[mi][ks] = *(const bf16x8*)&Q[hoff +
                (size_t)(qt * 128 + w * 32 + mi * 16 + l15) * HD + ks * 32 + l4 * 8];

    bf16x8 ones;
    #pragma unroll
    for (int j = 0; j < 8; j++) ones[j] = (short)0x3F80;   // bf16 1.0

    f32x4 po[2][4] = {};
    f32x4 pol[2] = {};

    const int srow = lane >> 3;           // row-in-8-group; == (tile row)&7
    const int schunk = (lane & 7) ^ srow; // XOR chunk swizzle (both K and V tiles)
    // K tile [64][64]: rows = keys kt*64 + w*16 + i*8 + srow, cols schunk*8 of HD
    const u16* kgl = Kg + hoff + (size_t)(w * 16 + srow) * HD + schunk * 8;
    // V tile [64][64]: rows = d = w*16 + i*8 + srow, cols kt*64 + schunk*8 of TT
    const u16* vgl = VT + (size_t)bh * (HD * TT) + (size_t)(w * 16 + srow) * TT + schunk * 8;
    const int ldst = (w * 16) * 64 + lane * 8;   // wave's linear LDS slot (both tiles)
    const size_t mbase = ((size_t)(b * TT + qt * 128 + w * 32 + l4 * 4)) * 64;
    const int shEven = 31 - l15, shOdd = 15 - l15;   // sign-extend shift per nt parity

    // prologue: stage tile 0 into buffer 0
    #pragma unroll
    for (int i = 0; i < 2; i++) {
        gload16(kgl + (size_t)(i * 8) * HD, &Ks[0][ldst + i * 8 * 64]);
        gload16(vgl + (size_t)(i * 8) * TT, &Vs[0][ldst + i * 8 * 64]);
    }
    __syncthreads();

    for (int kt = 0; kt < 32; kt++) {
        const int cur = kt & 1;
        // prefetch next tile into the other buffer (drained by end-of-tile barrier)
        if (kt < 31) {
            #pragma unroll
            for (int i = 0; i < 2; i++) {
                gload16(kgl + (size_t)((kt + 1) * 64 + i * 8) * HD, &Ks[cur ^ 1][ldst + i * 8 * 64]);
                gload16(vgl + (size_t)(i * 8) * TT + (kt + 1) * 64, &Vs[cur ^ 1][ldst + i * 8 * 64]);
            }
        }
        // mask words for this 64-key tile (2 mi x 4 r, uint2 each)
        uint2 mb[2][4];
        #pragma unroll
        for (int mi = 0; mi < 2; mi++)
            #pragma unroll
            for (int r = 0; r < 4; r++)
                mb[mi][r] = *(const uint2*)&mbits[mbase + (size_t)(mi * 16 + r) * 64 + kt * 2];

        // S = Q K^T (exp2-space): s[mi][nt], lane holds S[q=l4*4+r][key=nt*16+l15]
        f32x4 s[2][4];
        __builtin_amdgcn_s_setprio(1);
        #pragma unroll
        for (int nt = 0; nt < 4; nt++) {
            int krow = nt * 16 + l15;
            bf16x8 kf0 = *(const bf16x8*)&Ks[cur][krow * 64 + (((0 + l4) ^ (krow & 7)) * 8)];
            bf16x8 kf1 = *(const bf16x8*)&Ks[cur][krow * 64 + (((4 + l4) ^ (krow & 7)) * 8)];
            #pragma unroll
            for (int mi = 0; mi < 2; mi++) {
                f32x4 z = {0.f, 0.f, 0.f, 0.f};
                z = __builtin_amdgcn_mfma_f32_16x16x32_bf16(qf[mi][0], kf0, z, 0, 0, 0);
                s[mi][nt] = __builtin_amdgcn_mfma_f32_16x16x32_bf16(qf[mi][1], kf1, z, 0, 0, 0);
            }
        }
        __builtin_amdgcn_s_setprio(0);

        // no-max masked softmax numerator: p = exp2(s) & ext, truncate-pack to bf16
        // P rows are wave-private; in-wave ds ordering suffices (no barrier needed)
        #pragma unroll
        for (int mi = 0; mi < 2; mi++) {
            #pragma unroll
            for (int r = 0; r < 4; r++) {
                u32 mw[2] = {mb[mi][r].x, mb[mi][r].y};
                int prow = w * 32 + mi * 16 + l4 * 4 + r;
                u16* pw = &Ps[prow * 72 + l15];
                #pragma unroll
                for (int nt = 0; nt < 4; nt++) {
                    u32 word = mw[nt >> 1];
                    int sh = (nt & 1) ? shOdd : shEven;
                    u32 ext = (u32)(((int)(word << sh)) >> 31);   // 0 or 0xFFFFFFFF
                    float p = ex2(s[mi][nt][r]);
                    u32 pb = __builtin_bit_cast(u32, p) & ext;
                    pw[nt * 16] = (u16)(pb >> 16);
                }
            }
        }

        // PV + l-sum: A = own-wave P rows, B = V^T fragments (+ ones column)
        bf16x8 pf[2][2];
        #pragma unroll
        for (int mi = 0; mi < 2; mi++)
            #pragma unroll
            for (int ks = 0; ks < 2; ks++)
                pf[mi][ks] = *(const bf16x8*)&Ps[(w * 32 + mi * 16 + l15) * 72 + ks * 32 + l4 * 8];
        __builtin_amdgcn_s_setprio(1);
        #pragma unroll
        for (int nto = 0; nto < 4; nto++) {
            #pragma unroll
            for (int ks = 0; ks < 2; ks++) {
                int d = nto * 16 + l15;
                bf16x8 vf = *(const bf16x8*)&Vs[cur][d * 64 + (((ks * 4 + l4) ^ (d & 7)) * 8)];
                #pragma unroll
                for (int mi = 0; mi < 2; mi++)
                    po[mi][nto] = __builtin_amdgcn_mfma_f32_16x16x32_bf16(
                        pf[mi][ks], vf, po[mi][nto], 0, 0, 0);
            }
        }
        #pragma unroll
        for (int mi = 0; mi < 2; mi++)
            #pragma unroll
            for (int ks = 0; ks < 2; ks++)
                pol[mi] = __builtin_amdgcn_mfma_f32_16x16x32_bf16(pf[mi][ks], ones, pol[mi], 0, 0, 0);
        __builtin_amdgcn_s_setprio(0);
        __syncthreads();   // all waves done with buf[cur] K,V; prefetched buf[cur^1] drained
    }

    // epilogue: normalize and store bf16 [B][T][H*64]
    int h = bh & 15;
    #pragma unroll
    for (int mi = 0; mi < 2; mi++) {
        #pragma unroll
        for (int r = 0; r < 4; r++) {
            float lv = pol[mi][r];
            float inv = (lv > 0.f) ? (1.f / lv) : 0.f;
            int t = qt * 128 + w * 32 + mi * 16 + l4 * 4 + r;
            #pragma unroll
            for (int nto = 0; nto < 4; nto++)
                Og[((size_t)(b * TT + t)) * 1024 + h * 64 + nto * 16 + l15] =
                    bfu(po[mi][nto][r] * inv);
        }
    }
}

extern "C" void kernel_launch(void* const* d_in, const int* in_sizes, int n_in,
                              void* d_out, int out_size, void* d_ws, size_t ws_size,
                              hipStream_t stream) {
    const float* x   = (const float*)d_in[0];
    const float* aux = (const float*)d_in[1];
    const float* Wq  = (const float*)d_in[2];
    const float* bq  = (const float*)d_in[3];
    const float* Wk  = (const float*)d_in[4];
    const float* bk  = (const float*)d_in[5];
    const float* Wv  = (const float*)d_in[6];
    const float* bv  = (const float*)d_in[7];
    const float* Wo  = (const float*)d_in[8];
    const float* bo  = (const float*)d_in[9];
    const float* PEq = (const float*)d_in[10];
    const float* PEk = (const float*)d_in[11];
    const unsigned char* mask = (const unsigned char*)d_in[12];
    const int* fidx  = (const int*)d_in[13];
    float* out = (float*)d_out;

    char* ws = (char*)d_ws;
    u16* XA    = (u16*)(ws + 0);          // [4096][1280]; dead after gemm<0>
    u16* AttO  = (u16*)(ws + 0);          // aliases XA: [4096][1024]
    u16* WTall = (u16*)(ws + 10485760);   // [3072][1280]
    u16* WTo   = (u16*)(ws + 18350080);   // [1024][1024]
    u16* Qb    = (u16*)(ws + 20447232);   // [BH][T][64]
    u16* Kb    = (u16*)(ws + 28835840);
    u16* VTb   = (u16*)(ws + 45613056);   // [BH][64][T], written directly by gemm<0>
    u32* MB    = (u32*)(ws + 54001664);   // [B][T][64]

    prep<<<11264, 256, 0, stream>>>(x, aux, XA, Wq, Wk, Wv, Wo, WTall, WTo, mask, MB);

    gemm_bt<0><<<768, 256, 0, stream>>>(
        XA, WTall, 1280, bq, bk, bv, PEq, PEk, fidx, Qb, Kb, VTb, nullptr, nullptr);

    attn_fwd<<<512, 256, 0, stream>>>(Qb, Kb, VTb, MB, AttO);

    gemm_bt<1><<<dim3(32, 8), 256, 0, stream>>>(
        AttO, WTo, 1024, nullptr, nullptr, nullptr, nullptr, nullptr, nullptr,
        nullptr, nullptr, nullptr, out, bo);
}

// Round 15
// 140.878 us; speedup vs baseline: 1.0341x; 1.0341x over previous
//
#include <hip/hip_runtime.h>
#include <hip/hip_bf16.h>

typedef unsigned short u16;
typedef unsigned int u32;
typedef __attribute__((ext_vector_type(8))) short bf16x8;
typedef __attribute__((ext_vector_type(4))) float f32x4;

#define HD 64
#define NH 16
#define TT 2048
#define BB 2
#define CA 1280

__device__ __forceinline__ u16 bfu(float f) {
    u32 u = __builtin_bit_cast(u32, f);
    u32 r = u + 0x7fffu + ((u >> 16) & 1u);
    return (u16)(r >> 16);
}

__device__ __forceinline__ float ex2(float x) {
#if __has_builtin(__builtin_amdgcn_exp2f)
    return __builtin_amdgcn_exp2f(x);
#else
    return exp2f(x);
#endif
}

__device__ __forceinline__ void gload16(const void* g, void* l) {
    __builtin_amdgcn_global_load_lds(
        (const __attribute__((address_space(1))) unsigned int*)g,
        (__attribute__((address_space(3))) unsigned int*)l,
        16, 0, 0);
}

// ------------- fused prep: [0,5120) build_xaug | [5120,10240) wtrans x4 | [10240,11264) pack_mask
__global__ void prep(const float* __restrict__ x, const float* __restrict__ aux,
                     u16* __restrict__ xa,
                     const float* __restrict__ Wq, const float* __restrict__ Wk,
                     const float* __restrict__ Wv, const float* __restrict__ Wo,
                     u16* __restrict__ WTall, u16* __restrict__ WTo,
                     const unsigned char* __restrict__ m, u32* __restrict__ bits) {
    int bid = blockIdx.x;
    if (bid < 5120) {
        // ---- build x_aug (bf16 [4096][1280]) ----
        int i = bid * 256 + threadIdx.x;          // over 4096*320 float4 slots
        int row = i / 320;
        int c4 = i - row * 320;
        float4 v;
        if (c4 < 256) v = ((const float4*)x)[row * 256 + c4];
        else          v = ((const float4*)aux)[row * 64 + (c4 - 256)];
        ushort4 pk; pk.x = bfu(v.x); pk.y = bfu(v.y); pk.z = bfu(v.z); pk.w = bfu(v.w);
        ((ushort4*)xa)[i] = pk;
    } else if (bid < 10240) {
        // ---- weight transpose fp32 [Ksrc][1024] -> bf16 [1024][Kpad] ----
        int t = bid - 5120;
        int z = t / 1280;
        int inner = t - z * 1280;
        int kt = (inner % 40) * 32;
        int nt = (inner / 40) * 32;
        const float* src = (z == 0) ? Wq : (z == 1) ? Wk : (z == 2) ? Wv : Wo;
        u16* dst = (z == 3) ? WTo : WTall + (size_t)z * 1024 * 1280;
        int Ksrc = (z == 0 || z == 3) ? 1024 : 1280;
        int Kpad = (z == 3) ? 1024 : 1280;
        if (kt >= Kpad) return;
        __shared__ float tile[32][33];
        int r = threadIdx.x >> 5, c = threadIdx.x & 31;
        #pragma unroll
        for (int i = 0; i < 4; i++) {
            int k = kt + r + i * 8;
            tile[r + i * 8][c] = (k < Ksrc) ? src[(size_t)k * 1024 + nt + c] : 0.f;
        }
        __syncthreads();
        #pragma unroll
        for (int i = 0; i < 4; i++) {
            int n = nt + r + i * 8;
            dst[(size_t)n * Kpad + kt + c] = bfu(tile[c][r + i * 8]);
        }
    } else {
        // ---- pack mask -> bitmask [B][T][64 u32], runtime dtype detect ----
        __shared__ u32 modeSh;
        if (threadIdx.x == 0) modeSh = 0;
        __syncthreads();
        const u32* wp = (const u32*)m;
        u32 local = 0;
        for (int j = threadIdx.x; j < 2048; j += 256) {
            u32 v = wp[j];
            if (v == 0x3f800000u) local |= 2u;        // float32 1.0 word
            else if (v > 1u) local |= 1u;             // byte-packed bools
            if ((j & 1) && v != 0u) local |= 4u;      // odd word nonzero -> not int64
        }
        if (local) atomicOr(&modeSh, local);
        __syncthreads();
        u32 mode = modeSh;
        bool words32 = (mode & 2u) || (mode == 4u);   // float32 or int32
        bool bytes8 = !words32 && (mode & 1u);        // uint8 bools

        int i = (bid - 10240) * 256 + threadIdx.x;    // over B*T*64 = 262144
        size_t e0 = (size_t)i * 32;
        u32 r = 0;
        if (words32) {
            const uint4* q = (const uint4*)(wp + e0);
            #pragma unroll
            for (int j4 = 0; j4 < 8; j4++) {
                uint4 v = q[j4];
                if (v.x) r |= 1u << (j4 * 4 + 0);
                if (v.y) r |= 1u << (j4 * 4 + 1);
                if (v.z) r |= 1u << (j4 * 4 + 2);
                if (v.w) r |= 1u << (j4 * 4 + 3);
            }
        } else if (bytes8) {
            const unsigned char* p = m + e0;
            uint4 a = *(const uint4*)p;
            uint4 b = *(const uint4*)(p + 16);
            u32 words[8] = {a.x, a.y, a.z, a.w, b.x, b.y, b.z, b.w};
            #pragma unroll
            for (int jw = 0; jw < 8; jw++) {
                u32 xw = words[jw];
                r |= ((xw >> 0) & 1u) << (jw * 4 + 0);
                r |= ((xw >> 8) & 1u) << (jw * 4 + 1);
                r |= ((xw >> 16) & 1u) << (jw * 4 + 2);
                r |= ((xw >> 24) & 1u) << (jw * 4 + 3);
            }
        } else {
            #pragma unroll 4
            for (int j = 0; j < 32; j++)
                if (wp[(e0 + j) * 2]) r |= 1u << j;
        }
        bits[i] = r;
    }
}

// ---------------- GEMM: A[M][ld] bf16 row-major, Bt[N][ld] bf16 row-major ----------------
// Both modes: FLAT grid with XCD bm-strip swizzle (XCD x owns bm in [x*4,x*4+4) ->
// A-panels L2-resident per XCD; gemm1 additionally keeps WTo (2MB) resident).
// MODE 0 (768 blocks): sec = bn>>3 uniform per block:
//   sec 0: q = (acc+bias+PE)*0.125*log2e -> [B,H,T,64]; Keff=1024 (Wq pad x aux = 0)
//   sec 1: k = acc+bias+PE               -> [B,H,T,64]
//   sec 2: v = acc+bias, written TRANSPOSED -> VT [B,H,64,T]
// MODE 1 (256 blocks): fp32 out + bias
template <int MODE>
__global__ __launch_bounds__(256, 3) void gemm_bt(
    const u16* __restrict__ A, const u16* __restrict__ Bt, int K,
    const float* __restrict__ biasq, const float* __restrict__ biask,
    const float* __restrict__ biasv, const float* __restrict__ PEq,
    const float* __restrict__ PEk, const int* __restrict__ fidx,
    u16* __restrict__ qo, u16* __restrict__ ko, u16* __restrict__ vto,
    float* __restrict__ fo, const float* __restrict__ bo) {
    __shared__ u16 As[128 * 64];
    __shared__ u16 Bs[128 * 64];
    const int tid = threadIdx.x, lane = tid & 63, w = tid >> 6;
    const int l15 = lane & 15, l4 = lane >> 4;
    const int wm = w >> 1, wn = w & 1;
    const int bid = blockIdx.x;                    // flat
    const int bm = (bid & 7) * 4 + ((bid >> 3) & 3);   // XCD strip: 4 bm per XCD
    const int bn = bid >> 5;
    const int Keff = (MODE == 0 && (bn >> 3) == 0) ? 1024 : K;

    f32x4 acc[4][4] = {};

    const int srow = lane >> 3;
    const int schunk = (lane & 7) ^ srow;
    const u16* ag = A + (size_t)(bm * 128 + w * 32 + srow) * K + schunk * 8;
    const u16* bg = Bt + (size_t)(bn * 128 + w * 32 + srow) * K + schunk * 8;
    u16* asl = &As[(w * 32) * 64] + lane * 8;
    u16* bsl = &Bs[(w * 32) * 64] + lane * 8;

    for (int kt = 0; kt < Keff; kt += 64) {
        #pragma unroll
        for (int i = 0; i < 4; i++) {
            gload16(ag + (size_t)i * 8 * K + kt, asl + i * 8 * 64);
            gload16(bg + (size_t)i * 8 * K + kt, bsl + i * 8 * 64);
        }
        __syncthreads();
        #pragma unroll
        for (int ks = 0; ks < 2; ks++) {
            bf16x8 af[4], bfr[4];
            #pragma unroll
            for (int mi = 0; mi < 4; mi++) {
                int row = wm * 64 + mi * 16 + l15;
                af[mi] = *(const bf16x8*)&As[row * 64 + (((ks * 4 + l4) ^ (row & 7)) * 8)];
            }
            #pragma unroll
            for (int ni = 0; ni < 4; ni++) {
                int row = wn * 64 + ni * 16 + l15;
                bfr[ni] = *(const bf16x8*)&Bs[row * 64 + (((ks * 4 + l4) ^ (row & 7)) * 8)];
            }
            #pragma unroll
            for (int mi = 0; mi < 4; mi++)
                #pragma unroll
                for (int ni = 0; ni < 4; ni++)
                    acc[mi][ni] = __builtin_amdgcn_mfma_f32_16x16x32_bf16(
                        af[mi], bfr[ni], acc[mi][ni], 0, 0, 0);
        }
        __syncthreads();
    }

    if (MODE == 0) {
        int sec = bn >> 3;
        if (sec < 2) {
            const float* bias = sec ? biask : biasq;
            const float* PE   = sec ? PEk : PEq;
            u16* outp = sec ? ko : qo;
            float scl = sec ? 1.0f : 0.180336880111120419f;   // q: 0.125*log2(e)
            #pragma unroll
            for (int mi = 0; mi < 4; mi++) {
                #pragma unroll
                for (int r = 0; r < 4; r++) {
                    int m = bm * 128 + wm * 64 + mi * 16 + l4 * 4 + r;
                    int b = m >> 11, t = m & 2047;
                    int fi = fidx[m];
                    #pragma unroll
                    for (int ni = 0; ni < 4; ni++) {
                        int nn = (bn & 7) * 128 + wn * 64 + ni * 16 + l15;
                        float val = (acc[mi][ni][r] + bias[nn] + PE[(size_t)fi * 1024 + nn]) * scl;
                        outp[((size_t)(b * NH + (nn >> 6)) * TT + t) * HD + (nn & 63)] = bfu(val);
                    }
                }
            }
        } else {
            // V: bias + transposed write. t runs over r (consecutive) -> ushort4 store.
            int b = bm >> 4;
            int t0 = (bm & 15) * 128 + wm * 64;
            #pragma unroll
            for (int ni = 0; ni < 4; ni++) {
                int nn = (bn - 16) * 128 + wn * 64 + ni * 16 + l15;
                float bvv = biasv[nn];
                int h = nn >> 6, d = nn & 63;
                u16* dst = vto + ((size_t)((b * NH + h) * HD + d)) * TT + t0;
                #pragma unroll
                for (int mi = 0; mi < 4; mi++) {
                    ushort4 pk;
                    pk.x = bfu(acc[mi][ni][0] + bvv);
                    pk.y = bfu(acc[mi][ni][1] + bvv);
                    pk.z = bfu(acc[mi][ni][2] + bvv);
                    pk.w = bfu(acc[mi][ni][3] + bvv);
                    *(ushort4*)(dst + mi * 16 + l4 * 4) = pk;
                }
            }
        }
    } else {
        #pragma unroll
        for (int mi = 0; mi < 4; mi++) {
            #pragma unroll
            for (int r = 0; r < 4; r++) {
                int m = bm * 128 + wm * 64 + mi * 16 + l4 * 4 + r;
                #pragma unroll
                for (int ni = 0; ni < 4; ni++) {
                    int ng = bn * 128 + wn * 64 + ni * 16 + l15;
                    fo[(size_t)m * 1024 + ng] = acc[mi][ni][r] + bo[ng];
                }
            }
        }
    }
}

// ---------------- flash attention (r13 proven optimum: QBLK=128, 4 waves x 32 q) ------
// kf/vf fragment reads are w-independent -> 32q/wave feeds each kf/vf read into 2 MFMAs
// (mi=0,1): LDS demand per unit work -24% vs 16q/wave, 8 waves/CU, 3-barrier structure.
// grid flat 512 with XCD affinity: bh = (s&7)*4 + (s>>7), qt = (s>>3)&15 (K/V L2-resident,
// measured FETCH 70->14MB). no-max exp2 softmax; masked by AND; l-sum via MFMA ones.
// LDS: KPs union { K [128][64] 16KB | P [128][136] 34.8KB } + Vs [64][128] 16KB = 50KB.
__global__ __launch_bounds__(256, 2) void attn_fwd(
    const u16* __restrict__ Q, const u16* __restrict__ Kg,
    const u16* __restrict__ VT, const u32* __restrict__ mbits,
    u16* __restrict__ Og) {
    __shared__ u16 KPs[128 * 136];
    __shared__ u16 Vs[64 * 128];
    const int tid = threadIdx.x, lane = tid & 63, w = tid >> 6;
    const int l15 = lane & 15, l4 = lane >> 4;
    const int s_ = blockIdx.x;
    const int qt = (s_ >> 3) & 15;
    const int bh = (s_ & 7) * 4 + (s_ >> 7);
    const int b = bh >> 4;
    const size_t hoff = (size_t)bh * (TT * HD);

    // wave w owns q-rows qt*128 + w*32 + [0,32): two 16-row blocks (mi)
    bf16x8 qf[2][2];
    #pragma unroll
    for (int mi = 0; mi < 2; mi++)
        #pragma unroll
        for (int ks = 0; ks < 2; ks++)
            qf[mi][ks] = *(const bf16x8*)&Q[hoff +
                (size_t)(qt * 128 + w * 32 + mi * 16 + l15) * HD + ks * 32 + l4 * 8];

    bf16x8 ones;
    #pragma unroll
    for (int j = 0; j < 8; j++) ones[j] = (short)0x3F80;   // bf16 1.0

    f32x4 po[2][4] = {};
    f32x4 pol[2] = {};

    const int srow = lane >> 3;
    const int schunk = (lane & 7) ^ srow;
    const u16* kgl = Kg + hoff + (size_t)(w * 32 + srow) * HD + schunk * 8;
    u16* ksl = &KPs[(w * 32) * 64] + lane * 8;
    const size_t voff = (size_t)bh * (HD * TT);
    const size_t mbase = ((size_t)(b * TT + qt * 128 + w * 32 + l4 * 4)) * 64;
    const int shEven = 31 - l15, shOdd = 15 - l15;   // sign-extend shift per nt parity

    for (int kt = 0; kt < 16; kt++) {
        // prefetch mask rows (2 mi x 4 r) — consumed after 2 barriers
        uint4 mb[2][4];
        #pragma unroll
        for (int mi = 0; mi < 2; mi++)
            #pragma unroll
            for (int r = 0; r < 4; r++)
                mb[mi][r] = *(const uint4*)&mbits[mbase + (size_t)(mi * 16 + r) * 64 + kt * 4];

        // stage K tile [128][64] (XOR chunk-swizzled content, linear LDS): rows w*32..+32
        #pragma unroll
        for (int i = 0; i < 4; i++)
            gload16(kgl + (size_t)(kt * 128 + i * 8) * HD, ksl + i * 8 * 64);
        // stage V^T tile [64][128]: d-rows w*16..+16
        #pragma unroll
        for (int i = 0; i < 4; i++) {
            int d = w * 16 + i * 4 + l4;
            const u16* src = VT + voff + (size_t)d * TT + kt * 128 + ((l15 ^ (d & 15)) * 8);
            gload16(src, &Vs[(w * 16 + i * 4) * 128] + lane * 8);
        }
        __syncthreads();

        // S = Q K^T (exp2-space): s[mi][nt], lane holds S[q=l4*4+r][key=nt*16+l15]
        f32x4 s[2][8];
        __builtin_amdgcn_s_setprio(1);
        #pragma unroll
        for (int nt = 0; nt < 8; nt++) {
            int krow = nt * 16 + l15;
            bf16x8 kf0 = *(const bf16x8*)&KPs[krow * 64 + (((0 + l4) ^ (krow & 7)) * 8)];
            bf16x8 kf1 = *(const bf16x8*)&KPs[krow * 64 + (((4 + l4) ^ (krow & 7)) * 8)];
            #pragma unroll
            for (int mi = 0; mi < 2; mi++) {
                f32x4 z = {0.f, 0.f, 0.f, 0.f};
                z = __builtin_amdgcn_mfma_f32_16x16x32_bf16(qf[mi][0], kf0, z, 0, 0, 0);
                s[mi][nt] = __builtin_amdgcn_mfma_f32_16x16x32_bf16(qf[mi][1], kf1, z, 0, 0, 0);
            }
        }
        __builtin_amdgcn_s_setprio(0);
        __syncthreads();   // all waves done reading K region; safe to overwrite with P

        // no-max masked softmax numerator: p = exp2(s) & ext, truncate-pack to bf16
        #pragma unroll
        for (int mi = 0; mi < 2; mi++) {
            #pragma unroll
            for (int r = 0; r < 4; r++) {
                u32 mw[4] = {mb[mi][r].x, mb[mi][r].y, mb[mi][r].z, mb[mi][r].w};
                int prow = w * 32 + mi * 16 + l4 * 4 + r;
                u16* pw = &KPs[prow * 136 + l15];
                #pragma unroll
                for (int nt = 0; nt < 8; nt++) {
                    u32 word = mw[nt >> 1];
                    int sh = (nt & 1) ? shOdd : shEven;
                    u32 ext = (u32)(((int)(word << sh)) >> 31);   // 0 or 0xFFFFFFFF
                    float p = ex2(s[mi][nt][r]);
                    u32 pb = __builtin_bit_cast(u32, p) & ext;
                    pw[nt * 16] = (u16)(pb >> 16);
                }
            }
        }

        // PV + l-sum: A = own-wave P rows, B = V^T fragments (+ ones column)
        bf16x8 pf[2][4];
        #pragma unroll
        for (int mi = 0; mi < 2; mi++)
            #pragma unroll
            for (int ks = 0; ks < 4; ks++)
                pf[mi][ks] = *(const bf16x8*)&KPs[(w * 32 + mi * 16 + l15) * 136 + ks * 32 + l4 * 8];
        __builtin_amdgcn_s_setprio(1);
        #pragma unroll
        for (int nto = 0; nto < 4; nto++) {
            #pragma unroll
            for (int ks = 0; ks < 4; ks++) {
                int d = nto * 16 + l15;
                bf16x8 vf = *(const bf16x8*)&Vs[d * 128 + (((ks * 4 + l4) ^ (d & 15)) * 8)];
                #pragma unroll
                for (int mi = 0; mi < 2; mi++)
                    po[mi][nto] = __builtin_amdgcn_mfma_f32_16x16x32_bf16(
                        pf[mi][ks], vf, po[mi][nto], 0, 0, 0);
            }
        }
        #pragma unroll
        for (int mi = 0; mi < 2; mi++)
            #pragma unroll
            for (int ks = 0; ks < 4; ks++)
                pol[mi] = __builtin_amdgcn_mfma_f32_16x16x32_bf16(pf[mi][ks], ones, pol[mi], 0, 0, 0);
        __builtin_amdgcn_s_setprio(0);
        __syncthreads();   // P + Vs consumed before next tile's staging
    }

    // epilogue: normalize and store bf16 [B][T][H*64]
    int h = bh & 15;
    #pragma unroll
    for (int mi = 0; mi < 2; mi++) {
        #pragma unroll
        for (int r = 0; r < 4; r++) {
            float lv = pol[mi][r];
            float inv = (lv > 0.f) ? (1.f / lv) : 0.f;
            int t = qt * 128 + w * 32 + mi * 16 + l4 * 4 + r;
            #pragma unroll
            for (int nto = 0; nto < 4; nto++)
                Og[((size_t)(b * TT + t)) * 1024 + h * 64 + nto * 16 + l15] =
                    bfu(po[mi][nto][r] * inv);
        }
    }
}

extern "C" void kernel_launch(void* const* d_in, const int* in_sizes, int n_in,
                              void* d_out, int out_size, void* d_ws, size_t ws_size,
                              hipStream_t stream) {
    const float* x   = (const float*)d_in[0];
    const float* aux = (const float*)d_in[1];
    const float* Wq  = (const float*)d_in[2];
    const float* bq  = (const float*)d_in[3];
    const float* Wk  = (const float*)d_in[4];
    const float* bk  = (const float*)d_in[5];
    const float* Wv  = (const float*)d_in[6];
    const float* bv  = (const float*)d_in[7];
    const float* Wo  = (const float*)d_in[8];
    const float* bo  = (const float*)d_in[9];
    const float* PEq = (const float*)d_in[10];
    const float* PEk = (const float*)d_in[11];
    const unsigned char* mask = (const unsigned char*)d_in[12];
    const int* fidx  = (const int*)d_in[13];
    float* out = (float*)d_out;

    char* ws = (char*)d_ws;
    u16* XA    = (u16*)(ws + 0);          // [4096][1280]; dead after gemm<0>
    u16* AttO  = (u16*)(ws + 0);          // aliases XA: [4096][1024]
    u16* WTall = (u16*)(ws + 10485760);   // [3072][1280]
    u16* WTo   = (u16*)(ws + 18350080);   // [1024][1024]
    u16* Qb    = (u16*)(ws + 20447232);   // [BH][T][64]
    u16* Kb    = (u16*)(ws + 28835840);
    u16* VTb   = (u16*)(ws + 45613056);   // [BH][64][T], written directly by gemm<0>
    u32* MB    = (u32*)(ws + 54001664);   // [B][T][64]

    prep<<<11264, 256, 0, stream>>>(x, aux, XA, Wq, Wk, Wv, Wo, WTall, WTo, mask, MB);

    gemm_bt<0><<<768, 256, 0, stream>>>(
        XA, WTall, 1280, bq, bk, bv, PEq, PEk, fidx, Qb, Kb, VTb, nullptr, nullptr);

    attn_fwd<<<512, 256, 0, stream>>>(Qb, Kb, VTb, MB, AttO);

    gemm_bt<1><<<256, 256, 0, stream>>>(
        AttO, WTo, 1024, nullptr, nullptr, nullptr, nullptr, nullptr, nullptr,
        nullptr, nullptr, nullptr, out, bo);
}